// Round 11
// baseline (141.950 us; speedup 1.0000x reference)
//
#include <hip/hip_runtime.h>
#include <hip/hip_bf16.h>

// Problem: SelfAttention1d  B=4, L=2048, C=256, H=8, D=32.
// dtypes: inputs fp32, output fp32 (PASS r7-r10; r10 = 141us, attn 94us).
// ws layout (bf16): Q (B,H,L,D) | K (B,H,L,D) | Vt (B,H,D,L) | O (B,L,C) = 16MB.
// Round 11: attn TLP fix — KV-split 2 (sum-softmax partials are additive),
// 512-thread blocks / 8 waves (waves 0-3: keys [0,1024), 4-7: [1024,2048)),
// one barrier + LDS pairwise combine. 8 waves/SIMD (launch_bounds(512,8)).

typedef __bf16 bf16x4 __attribute__((ext_vector_type(4)));
typedef __bf16 bf16x8 __attribute__((ext_vector_type(8)));
typedef float  f32x4  __attribute__((ext_vector_type(4)));

#define MFMA16(a, b, c) __builtin_amdgcn_mfma_f32_16x16x32_bf16((a), (b), (c), 0, 0, 0)

static constexpr int Bsz = 4, L = 2048, C = 256, H = 8, D = 32;
static constexpr float SCALE = 0.17677669529663687f;   // 32^-0.5
static constexpr float LOG2E = 1.44269504088896f;
static constexpr float QSCALE = SCALE * LOG2E;         // exp2(S) = softmax exp

__device__ inline bf16x8 load_cvt8(const float* __restrict__ p) {
    f32x4 a = *(const f32x4*)(p);
    f32x4 b = *(const f32x4*)(p + 4);
    bf16x8 r;
    r[0] = (__bf16)a[0]; r[1] = (__bf16)a[1]; r[2] = (__bf16)a[2]; r[3] = (__bf16)a[3];
    r[4] = (__bf16)b[0]; r[5] = (__bf16)b[1]; r[6] = (__bf16)b[2]; r[7] = (__bf16)b[3];
    return r;
}

// ---------------------------------------------------------------------------
// Kernel 1: QKV GEMM.  X(8192,256) @ Wqkv(768,256)^T + b -> split into Q,K,Vt.
// Q pre-scaled by SCALE*LOG2E so attention uses raw exp2.
// ---------------------------------------------------------------------------
__global__ __launch_bounds__(256) void qkv_gemm(
    const float* __restrict__ X, const float* __restrict__ W,
    const float* __restrict__ Bq,
    __bf16* __restrict__ Qw, __bf16* __restrict__ Kw, __bf16* __restrict__ Vt)
{
    const int K = 256;
    const int bm = blockIdx.x & 63, bn = blockIdx.x >> 6;
    const int tid = threadIdx.x, wid = tid >> 6, lane = tid & 63;
    const int lr = lane & 15, lh = lane >> 4;
    const int m0 = bm * 128 + (wid >> 1) * 64;
    const int n0 = bn * 64 + (wid & 1) * 32;

    f32x4 acc[4][2] = {};
    const float* Arow = X + (size_t)(m0 + lr) * K + lh * 8;
    const float* Brow = W + (size_t)(n0 + lr) * K + lh * 8;

    #pragma unroll
    for (int k0 = 0; k0 < 256; k0 += 32) {
        bf16x8 a[4], b[2];
        #pragma unroll
        for (int mt = 0; mt < 4; ++mt) a[mt] = load_cvt8(Arow + mt * 16 * K + k0);
        #pragma unroll
        for (int nt = 0; nt < 2; ++nt) b[nt] = load_cvt8(Brow + nt * 16 * K + k0);
        #pragma unroll
        for (int mt = 0; mt < 4; ++mt)
            #pragma unroll
            for (int nt = 0; nt < 2; ++nt)
                acc[mt][nt] = MFMA16(a[mt], b[nt], acc[mt][nt]);
    }

    #pragma unroll
    for (int mt = 0; mt < 4; ++mt) {
        #pragma unroll
        for (int nt = 0; nt < 2; ++nt) {
            const int n = n0 + nt * 16 + lr;
            const float bias = Bq[n];
            const int h = n / 96, r = n % 96, which = r >> 5, d = r & 31;
            #pragma unroll
            for (int i = 0; i < 4; ++i) {
                const int m  = m0 + mt * 16 + lh * 4 + i;
                const int bb = m >> 11, li = m & 2047;
                const int bh = bb * H + h;
                const float v = acc[mt][nt][i] + bias;
                if (which == 0)
                    Qw[((size_t)bh * L + li) * D + d] = (__bf16)(v * QSCALE);
                else if (which == 1)
                    Kw[((size_t)bh * L + li) * D + d] = (__bf16)v;
                else
                    Vt[((size_t)bh * D + d) * L + li] = (__bf16)v;
            }
        }
    }
}

// ---------------------------------------------------------------------------
// Kernel 2: flash attention, KV-split 2.
// grid 1024 x 512 thr (8 waves). XCD swizzle: bh = (bid&7)*4 + ((bid>>3)&3),
// qt = bid>>5. Wave w: q-rows qt*64 + (w&3)*16 .. +16, keys half (w>>2).
// Combine: wave w+4 publishes (of, sum) via LDS; wave w adds, normalizes, stores.
// ---------------------------------------------------------------------------
__global__ __launch_bounds__(512, 8) void attn_fwd(
    const __bf16* __restrict__ Qw, const __bf16* __restrict__ Kw,
    const __bf16* __restrict__ Vt, __bf16* __restrict__ O)
{
    __shared__ __align__(16) __bf16 Plds[8][16][72];
    __shared__ __align__(16) f32x4  Cof[4][64][2];
    __shared__ float Csum[4][64];

    const int bid = blockIdx.x;
    const int bh = ((bid & 7) << 2) | ((bid >> 3) & 3);
    const int qt = bid >> 5;
    const int tid = threadIdx.x, wid = tid >> 6, lane = tid & 63;
    const int lr = lane & 15, lh = lane >> 4;
    const int q0 = qt * 64 + (wid & 3) * 16;
    const int kvbase = (wid >> 2) * 1024;            // KV half

    const __bf16* Qb = Qw + (size_t)bh * L * D;
    const __bf16* Kb = Kw + (size_t)bh * L * D;
    const __bf16* Vb = Vt + (size_t)bh * D * L;

    // Q fragment: q-row = lr, d = lh*8..+8 (MFMA B operand)
    const bf16x8 qf = *(const bf16x8*)(Qb + (size_t)(q0 + lr) * D + lh * 8);

    f32x4 of[2] = {};
    float sumpart = 0.f;
    const f32x4 zero = {0.f, 0.f, 0.f, 0.f};

    for (int kv = 0; kv < 1024; kv += 64) {
        const int kv0 = kvbase + kv;
        bf16x8 kf[4], vf[2][2];
        #pragma unroll
        for (int t = 0; t < 4; ++t)
            kf[t] = *(const bf16x8*)(Kb + (size_t)(kv0 + 16 * t + lr) * D + lh * 8);
        #pragma unroll
        for (int od = 0; od < 2; ++od)
            #pragma unroll
            for (int ks = 0; ks < 2; ++ks)
                vf[od][ks] = *(const bf16x8*)(Vb + (size_t)(od * 16 + lr) * L +
                                              kv0 + ks * 32 + lh * 8);

        #pragma unroll
        for (int t = 0; t < 4; ++t) {
            // S^T sub-tile: A = K rows (m = k), B = Q (n = q)
            const f32x4 s = MFMA16(kf[t], qf, zero);
            bf16x4 pb;
            #pragma unroll
            for (int i = 0; i < 4; ++i) {
                const float p = exp2f(s[i]);         // Q pre-scaled
                sumpart += p;
                pb[i] = (__bf16)p;
            }
            *(bf16x4*)(&Plds[wid][lr][16 * t + lh * 4]) = pb;   // P[q=lr][k]
        }

        // per-wave LDS round-trip (wave-internal DS in-order; may-alias safe)
        bf16x8 pa[2];
        pa[0] = *(const bf16x8*)(&Plds[wid][lr][lh * 8]);
        pa[1] = *(const bf16x8*)(&Plds[wid][lr][32 + lh * 8]);

        #pragma unroll
        for (int od = 0; od < 2; ++od)
            #pragma unroll
            for (int ks = 0; ks < 2; ++ks)
                of[od] = MFMA16(pa[ks], vf[od][ks], of[od]);
    }

    // finish row sums within wave (q = lr held by the 4 lh lanes)
    float sumw = sumpart;
    sumw += __shfl_xor(sumw, 16);
    sumw += __shfl_xor(sumw, 32);

    // cross-half combine: high waves publish, low waves accumulate
    if (wid >= 4) {
        Cof[wid - 4][lane][0] = of[0];
        Cof[wid - 4][lane][1] = of[1];
        Csum[wid - 4][lane] = sumw;
    }
    __syncthreads();
    if (wid < 4) {
        of[0] += Cof[wid][lane][0];
        of[1] += Cof[wid][lane][1];
        sumw  += Csum[wid][lane];

        const int b = bh >> 3, h = bh & 7;
        #pragma unroll
        for (int i = 0; i < 4; ++i) {
            const float rs = __shfl(sumw, lh * 4 + i);
            const float inv = 1.f / rs;
            const int row = q0 + lh * 4 + i;
            const size_t base = ((size_t)b * L + row) * C + h * D;
            O[base + lr]      = (__bf16)(of[0][i] * inv);
            O[base + 16 + lr] = (__bf16)(of[1][i] * inv);
        }
    }
}

// ---------------------------------------------------------------------------
// Kernel 3: output projection. O(8192,256)bf16 @ Wp(256,256)^T f32 + b -> f32.
// ---------------------------------------------------------------------------
__global__ __launch_bounds__(256) void proj_gemm(
    const __bf16* __restrict__ A, const float* __restrict__ W,
    const float* __restrict__ Bp, float* __restrict__ Out)
{
    const int K = 256;
    const int bm = blockIdx.x & 63, bn = blockIdx.x >> 6;
    const int tid = threadIdx.x, wid = tid >> 6, lane = tid & 63;
    const int lr = lane & 15, lh = lane >> 4;
    const int m0 = bm * 128 + (wid >> 1) * 64;
    const int n0 = bn * 64 + (wid & 1) * 32;

    f32x4 acc[4][2] = {};
    const __bf16* Arow = A + (size_t)(m0 + lr) * K + lh * 8;
    const float*  Brow = W + (size_t)(n0 + lr) * K + lh * 8;

    #pragma unroll
    for (int k0 = 0; k0 < 256; k0 += 32) {
        bf16x8 a[4], b[2];
        #pragma unroll
        for (int mt = 0; mt < 4; ++mt) a[mt] = *(const bf16x8*)(Arow + mt * 16 * K + k0);
        #pragma unroll
        for (int nt = 0; nt < 2; ++nt) b[nt] = load_cvt8(Brow + nt * 16 * K + k0);
        #pragma unroll
        for (int mt = 0; mt < 4; ++mt)
            #pragma unroll
            for (int nt = 0; nt < 2; ++nt)
                acc[mt][nt] = MFMA16(a[mt], b[nt], acc[mt][nt]);
    }

    #pragma unroll
    for (int mt = 0; mt < 4; ++mt) {
        #pragma unroll
        for (int nt = 0; nt < 2; ++nt) {
            const int n = n0 + nt * 16 + lr;
            const float bias = Bp[n];
            #pragma unroll
            for (int i = 0; i < 4; ++i) {
                const int m = m0 + mt * 16 + lh * 4 + i;
                Out[(size_t)m * 256 + n] = acc[mt][nt][i] + bias;
            }
        }
    }
}

__global__ void fatal_flag(float* Out, int n, float v) {
    int i = blockIdx.x * blockDim.x + threadIdx.x;
    if (i < n) Out[i] = (i == 0) ? v : 0.f;
}

// ---------------------------------------------------------------------------
extern "C" void kernel_launch(void* const* d_in, const int* in_sizes, int n_in,
                              void* d_out, int out_size, void* d_ws, size_t ws_size,
                              hipStream_t stream)
{
    float* out = (float*)d_out;

    const float *x = nullptr, *w_qkv = nullptr, *b_qkv = nullptr,
                *w_proj = nullptr, *b_proj = nullptr;
    for (int i = 0; i < n_in; ++i) {
        switch (in_sizes[i]) {
            case 2097152: x      = (const float*)d_in[i]; break;
            case 196608:  w_qkv  = (const float*)d_in[i]; break;
            case 768:     b_qkv  = (const float*)d_in[i]; break;
            case 65536:   w_proj = (const float*)d_in[i]; break;
            case 256:     b_proj = (const float*)d_in[i]; break;
        }
    }
    if (!x || !w_qkv || !b_qkv || !w_proj || !b_proj) {
        fatal_flag<<<dim3((out_size + 255) / 256), dim3(256), 0, stream>>>(out, out_size, 3e9f);
        return;
    }

    const size_t SEG = (size_t)Bsz * H * L * D;      // 2M elems
    if (ws_size < 4 * SEG * sizeof(__bf16)) {
        fatal_flag<<<dim3((out_size + 255) / 256), dim3(256), 0, stream>>>(out, out_size, 1e9f);
        return;
    }

    __bf16* ws = (__bf16*)d_ws;
    __bf16* Qw = ws;
    __bf16* Kw = ws + SEG;
    __bf16* Vt = ws + 2 * SEG;
    __bf16* Ob = ws + 3 * SEG;

    qkv_gemm<<<dim3(768), dim3(256), 0, stream>>>(x, w_qkv, b_qkv, Qw, Kw, Vt);
    attn_fwd<<<dim3(1024), dim3(512), 0, stream>>>(Qw, Kw, Vt, Ob);
    proj_gemm<<<dim3(256), dim3(256), 0, stream>>>(Ob, w_proj, b_proj, out);
}